// Round 13
// baseline (190.001 us; speedup 1.0000x reference)
//
#include <hip/hip_runtime.h>
#include <math.h>

// Problem constants
#define NRAYS        32768
#define MARCH_ITERS  64
#define EPS_         1e-4f
#define STEP_        ((1.0f + 1.0f/64.0f) / 64.0f)   // exact in fp32

typedef __attribute__((ext_vector_type(8)))  short    short8;   // 8 bf16
typedef __attribute__((ext_vector_type(4)))  float    float4v;  // C/D frag
typedef __attribute__((ext_vector_type(4)))  unsigned uint4v;

__device__ __forceinline__ short8 mk_frag(unsigned p0, unsigned p1,
                                          unsigned p2, unsigned p3) {
    uint4v v = {p0, p1, p2, p3};
    return __builtin_bit_cast(short8, v);
}

// One v_perm_b32: low16 = trunc-bf16(a), high16 = trunc-bf16(b).
__device__ __forceinline__ unsigned packbf(unsigned a, unsigned b) {
    return __builtin_amdgcn_perm(b, a, 0x07060302u);
}

// Exact 3-way truncation split: x == hi + mid + lo bit-exactly in fp32.
struct Split3 { unsigned h, m, l; };
__device__ __forceinline__ Split3 split3(float x) {
    unsigned xu = __float_as_uint(x);
    float xh = __uint_as_float(xu & 0xFFFF0000u);
    float r  = x - xh;                        // exact
    unsigned ru = __float_as_uint(r);
    float xm = __uint_as_float(ru & 0xFFFF0000u);
    float r2 = r - xm;                        // exact, fits bf16
    return { xu, ru, __float_as_uint(r2) };
}

// 2-way split: hi + residual (packbf of r truncates -> the mid limb).
struct Split2 { unsigned h, r; };
__device__ __forceinline__ Split2 split2(float x) {
    unsigned xu = __float_as_uint(x);
    float xh = __uint_as_float(xu & 0xFFFF0000u);
    float rr = x - xh;                        // exact residual
    return { xu, __float_as_uint(rr) };
}

// Wave-specialized (R11/R12 structure). R13: march's A2m (W1 mid-limb frags)
// parked in LDS — written once, ds_read_b128 per iteration — converting a
// 64-iteration loop-carried live range (32 regs) into a per-iter transient,
// to fit the 168-reg cap of 3 waves/SIMD without scratch spill.
// 128-thread blocks: wave0 = march (serial), wave1 = tput (65 indep evals).
// MFMA layouts (R6-verified): A[row=lane&15][k=quad*8+j],
// B[k=quad*8+j][col=lane&15], C/D col=lane&15 row=quad*4+reg.
// L1 hidden assignment H(t,q,r)=32*(t>>1)+8q+4*(t&1)+r -> in-lane C1->B2.
// Precision: march L2 = 3 products (m,h)(h,m)(h,h); tput L2 = 2 products.
__global__ __launch_bounds__(128, 3) void sdf_lds_k(
    const float* __restrict__ rays,
    const float* __restrict__ W0,  const float* __restrict__ b0,
    const float* __restrict__ W1,  const float* __restrict__ b1,
    const float* __restrict__ W2,  const float* __restrict__ b2,
    const float* __restrict__ Wr0, const float* __restrict__ br0,
    const float* __restrict__ Wr1, const float* __restrict__ br1,
    float* __restrict__ out)
{
    __shared__ uint4v a2mLds[8 * 64];         // 8 KB: 8 frags x 64 lanes

    const int lane = threadIdx.x & 63;
    const int kind = threadIdx.x >> 6;        // 0 = march, 1 = tput
    const int quad = lane >> 4;
    const int m    = lane & 15;
    const int rayBase = blockIdx.x * 16;

    // ---- per-lane ray (ray = rayBase + m, replicated over quads) ----
    const float* rp = rays + (rayBase + m) * 6;
    const float ox = rp[0], oy = rp[1], oz = rp[2];
    const float dx = rp[3], dy = rp[4], dz = rp[5];

    // ---- A1: exact W0^T/b0 limbs, uniform per-quad K-slots (R9-verified) ----
    short8 A1[4];
    {
        const float* wbase = (quad == 0) ? W0 : (quad == 1) ? (W0 + 64)
                           : (quad == 2) ? (W0 + 128) : b0;
        #pragma unroll
        for (int t = 0; t < 4; ++t) {
            int j = 32 * (t >> 1) + 8 * (m >> 2) + 4 * (t & 1) + (m & 3);
            Split3 s = split3(wbase[j]);
            unsigned hh = packbf(s.h, s.h);
            unsigned hm = packbf(s.h, s.m);
            unsigned ml = packbf(s.m, s.l);
            unsigned l0 = packbf(s.l, 0u);
            bool is3 = (quad == 3);
            A1[t] = mk_frag(is3 ? hm : hh, is3 ? l0 : hm, is3 ? 0u : ml, 0u);
        }
    }

    // ---- A2h: W1^T hi limb (both branches use it; 32 frag-regs) ----
    short8 A2h[2][4];
    #pragma unroll
    for (int h = 0; h < 2; ++h)
        #pragma unroll
        for (int t = 0; t < 4; ++t) {
            unsigned ph[4];
            #pragma unroll
            for (int jp = 0; jp < 4; ++jp) {
                int k0 = 32 * h + quad * 8 + 2 * jp;
                int j2 = 16 * t + m;
                ph[jp] = packbf(__float_as_uint(W1[k0 * 64 + j2]),
                                __float_as_uint(W1[(k0 + 1) * 64 + j2]));
            }
            A2h[h][t] = mk_frag(ph[0], ph[1], ph[2], ph[3]);
        }

    // ---- b1 (C2 init) and W2 (L3), per-lane rows j2 = 16t+4q+r ----
    float4v b1v[4], w2v[4];
    #pragma unroll
    for (int t = 0; t < 4; ++t) {
        int base = 16 * t + 4 * quad;
        b1v[t] = (float4v){b1[base], b1[base + 1], b1[base + 2], b1[base + 3]};
        w2v[t] = (float4v){W2[base], W2[base + 1], W2[base + 2], W2[base + 3]};
    }
    const float b2s = b2[0];
    const float4v z4 = {0.f, 0.f, 0.f, 0.f};

    // ---- branchless exact B1 build (R9/R10-verified) ----
    auto buildB1 = [&](float px, float py, float pz) -> short8 {
        float c = (quad == 0) ? px : (quad == 1) ? py : pz;
        Split3 s = split3(c);
        unsigned d0 = packbf(s.h, s.m);
        unsigned d1 = packbf(s.l, s.h);
        unsigned d2 = packbf(s.m, s.h);
        if (quad == 3) { d0 = 0x3F803F80u; d1 = 0x00003F80u; d2 = 0u; }
        return mk_frag(d0, d1, d2, 0u);
    };

    // ---- shared front-end: pos -> exact L1 -> relu -> split2 pack ----
    auto front = [&](float px, float py, float pz, short8* BH, short8* BM) {
        short8 B1 = buildB1(px, py, pz);
        float4v C1[4];
        #pragma unroll
        for (int t = 0; t < 4; ++t)
            C1[t] = __builtin_amdgcn_mfma_f32_16x16x32_bf16(A1[t], B1, z4, 0, 0, 0);
        unsigned PH[4][2], PM[4][2];
        #pragma unroll
        for (int t = 0; t < 4; ++t) {
            float v0 = fmaxf(C1[t][0], 0.f), v1 = fmaxf(C1[t][1], 0.f);
            float v2 = fmaxf(C1[t][2], 0.f), v3 = fmaxf(C1[t][3], 0.f);
            unsigned u0 = __float_as_uint(v0), u1 = __float_as_uint(v1);
            unsigned u2 = __float_as_uint(v2), u3 = __float_as_uint(v3);
            PH[t][0] = packbf(u0, u1); PH[t][1] = packbf(u2, u3);
            float r0 = v0 - __uint_as_float(u0 & 0xFFFF0000u);
            float r1 = v1 - __uint_as_float(u1 & 0xFFFF0000u);
            float r2 = v2 - __uint_as_float(u2 & 0xFFFF0000u);
            float r3 = v3 - __uint_as_float(u3 & 0xFFFF0000u);
            PM[t][0] = packbf(__float_as_uint(r0), __float_as_uint(r1));
            PM[t][1] = packbf(__float_as_uint(r2), __float_as_uint(r3));
        }
        #pragma unroll
        for (int h = 0; h < 2; ++h) {
            BH[h] = mk_frag(PH[2 * h][0], PH[2 * h][1],
                            PH[2 * h + 1][0], PH[2 * h + 1][1]);
            BM[h] = mk_frag(PM[2 * h][0], PM[2 * h][1],
                            PM[2 * h + 1][0], PM[2 * h + 1][1]);
        }
    };

    // ---- L3: in-lane relu*W2, 2 cross-quad shuffles -> d at every lane ----
    auto l3 = [&](const float4v* C2) -> float {
        float q0 = 0.f, q1 = 0.f, q2 = 0.f, q3 = 0.f;
        #pragma unroll
        for (int t = 0; t < 4; ++t) {
            q0 = fmaf(fmaxf(C2[t][0], 0.f), w2v[t][0], q0);
            q1 = fmaf(fmaxf(C2[t][1], 0.f), w2v[t][1], q1);
            q2 = fmaf(fmaxf(C2[t][2], 0.f), w2v[t][2], q2);
            q3 = fmaf(fmaxf(C2[t][3], 0.f), w2v[t][3], q3);
        }
        float part = (q0 + q1) + (q2 + q3);
        part += __shfl_xor(part, 16, 64);
        part += __shfl_xor(part, 32, 64);
        return b2s + part;
    };

    if (kind == 0) {
        // =================== MARCH wave: 64 sequential evals ===============
        // Build A2m (W1 mid limb) and PARK IT IN LDS (write once).
        #pragma unroll
        for (int h = 0; h < 2; ++h)
            #pragma unroll
            for (int t = 0; t < 4; ++t) {
                unsigned pm[4];
                #pragma unroll
                for (int jp = 0; jp < 4; ++jp) {
                    int k0 = 32 * h + quad * 8 + 2 * jp;
                    int j2 = 16 * t + m;
                    Split2 a = split2(W1[k0 * 64 + j2]);
                    Split2 b = split2(W1[(k0 + 1) * 64 + j2]);
                    pm[jp] = packbf(a.r, b.r);   // trunc(residual) == mid limb
                }
                a2mLds[(h * 4 + t) * 64 + lane] = (uint4v){pm[0], pm[1], pm[2], pm[3]};
            }

        bool  hit = false;
        float cd  = 0.f;
        #pragma unroll 1
        for (int it = 0; it < MARCH_ITERS; ++it) {
            if (__all(hit)) break;
            short8 BH[2], BM[2];
            front(fmaf(dx, cd, ox), fmaf(dy, cd, oy), fmaf(dz, cd, oz), BH, BM);
            // L2: 3 products, small first: (m,h)(h,m)(h,h); 24 MFMAs.
            // A2m limbs stream from LDS (per-iter transient, not loop-carried).
            float4v C2[4];
            #pragma unroll
            for (int t = 0; t < 4; ++t) C2[t] = b1v[t];
            #pragma unroll
            for (int h = 0; h < 2; ++h)
                #pragma unroll
                for (int t = 0; t < 4; ++t) {
                    short8 a2m = __builtin_bit_cast(short8,
                                     a2mLds[(h * 4 + t) * 64 + lane]);
                    C2[t] = __builtin_amdgcn_mfma_f32_16x16x32_bf16(
                        a2m, BH[h], C2[t], 0, 0, 0);
                }
            #pragma unroll
            for (int h = 0; h < 2; ++h)
                #pragma unroll
                for (int t = 0; t < 4; ++t)
                    C2[t] = __builtin_amdgcn_mfma_f32_16x16x32_bf16(
                        A2h[h][t], BM[h], C2[t], 0, 0, 0);
            #pragma unroll
            for (int h = 0; h < 2; ++h)
                #pragma unroll
                for (int t = 0; t < 4; ++t)
                    C2[t] = __builtin_amdgcn_mfma_f32_16x16x32_bf16(
                        A2h[h][t], BH[h], C2[t], 0, 0, 0);
            float dm = l3(C2);
            bool c = (dm < EPS_) && (cd >= 0.f) && (cd <= 1.f);
            hit = hit || c;
            if (!hit) cd += dm;
        }

        // ---- reflection net: quad q handles hidden j in [16q, 16q+16) ----
        const float px = fmaf(dx, cd, ox), py = fmaf(dy, cd, oy), pz = fmaf(dz, cd, oz);
        float r0 = 0.f, r1 = 0.f, r2 = 0.f;
        #pragma unroll 4
        for (int jj = 0; jj < 16; ++jj) {
            int j = quad * 16 + jj;
            float a = fmaf(px, Wr0[j],
                      fmaf(py, Wr0[64 + j],
                      fmaf(pz, Wr0[128 + j],
                      fmaf(dx, Wr0[192 + j],
                      fmaf(dy, Wr0[256 + j],
                      fmaf(dz, Wr0[320 + j], br0[j]))))));
            a = fmaxf(a, 0.f);
            r0 = fmaf(a, Wr1[j * 3 + 0], r0);
            r1 = fmaf(a, Wr1[j * 3 + 1], r1);
            r2 = fmaf(a, Wr1[j * 3 + 2], r2);
        }
        r0 += __shfl_xor(r0, 16, 64); r0 += __shfl_xor(r0, 32, 64);
        r1 += __shfl_xor(r1, 16, 64); r1 += __shfl_xor(r1, 32, 64);
        r2 += __shfl_xor(r2, 16, 64); r2 += __shfl_xor(r2, 32, 64);
        r0 = 1.f / (1.f + expf(-(r0 + br1[0])));
        r1 = 1.f / (1.f + expf(-(r1 + br1[1])));
        r2 = 1.f / (1.f + expf(-(r2 + br1[2])));
        if (!hit) { r0 = 0.f; r1 = 0.f; r2 = 0.f; }
        if (lane < 16) {
            float* op = out + (rayBase + lane) * 4;
            op[0] = r0; op[1] = r1; op[2] = r2;
        }
    } else {
        // =================== TPUT wave: 65 independent evals ===============
        // i=0 at origin (== reference curr_min0), then t = STEP*i.
        // No manual pipeline regs; unroll-2 lets the compiler interleave.
        float cm = 3.4e38f;
        #pragma unroll 2
        for (int i = 0; i <= 64; ++i) {
            float ti = STEP_ * (float)i;
            short8 BH[2], BM[2];
            front(fmaf(dx, ti, ox), fmaf(dy, ti, oy), fmaf(dz, ti, oz), BH, BM);
            // L2: 2 products (h,m)(h,h); 16 MFMAs
            float4v C2[4];
            #pragma unroll
            for (int t = 0; t < 4; ++t) C2[t] = b1v[t];
            #pragma unroll
            for (int h = 0; h < 2; ++h)
                #pragma unroll
                for (int t = 0; t < 4; ++t)
                    C2[t] = __builtin_amdgcn_mfma_f32_16x16x32_bf16(
                        A2h[h][t], BM[h], C2[t], 0, 0, 0);
            #pragma unroll
            for (int h = 0; h < 2; ++h)
                #pragma unroll
                for (int t = 0; t < 4; ++t)
                    C2[t] = __builtin_amdgcn_mfma_f32_16x16x32_bf16(
                        A2h[h][t], BH[h], C2[t], 0, 0, 0);
            float dt = l3(C2);
            cm = fminf(cm, dt);
        }
        if (lane < 16)
            out[(rayBase + lane) * 4 + 3] = cm;
    }
}

extern "C" void kernel_launch(void* const* d_in, const int* in_sizes, int n_in,
                              void* d_out, int out_size, void* d_ws, size_t ws_size,
                              hipStream_t stream) {
    const float* rays = (const float*)d_in[0];
    const float* W0   = (const float*)d_in[1];
    const float* b0   = (const float*)d_in[2];
    const float* W1   = (const float*)d_in[3];
    const float* b1   = (const float*)d_in[4];
    const float* W2   = (const float*)d_in[5];
    const float* b2   = (const float*)d_in[6];
    const float* Wr0  = (const float*)d_in[7];
    const float* br0  = (const float*)d_in[8];
    const float* Wr1  = (const float*)d_in[9];
    const float* br1  = (const float*)d_in[10];
    float* out = (float*)d_out;

    // 2048 blocks x 128 threads: wave0 = march, wave1 = tput per 16 rays.
    // 4096 waves; 3 waves/SIMD; A2m in LDS (8 KB/block) to avoid spill.
    hipLaunchKernelGGL(sdf_lds_k, dim3(NRAYS / 16), dim3(128), 0, stream,
                       rays, W0, b0, W1, b1, W2, b2, Wr0, br0, Wr1, br1, out);
}

// Round 14
// 186.182 us; speedup vs baseline: 1.0205x; 1.0205x over previous
//
#include <hip/hip_runtime.h>
#include <math.h>

// Problem constants
#define NRAYS        32768
#define MARCH_ITERS  64
#define EPS_         1e-4f
#define STEP_        ((1.0f + 1.0f/64.0f) / 64.0f)   // exact in fp32

typedef __attribute__((ext_vector_type(8)))  short    short8;   // 8 bf16
typedef __attribute__((ext_vector_type(4)))  float    float4v;  // C/D frag
typedef __attribute__((ext_vector_type(4)))  unsigned uint4v;

__device__ __forceinline__ short8 mk_frag(unsigned p0, unsigned p1,
                                          unsigned p2, unsigned p3) {
    uint4v v = {p0, p1, p2, p3};
    return __builtin_bit_cast(short8, v);
}

// One v_perm_b32: low16 = trunc-bf16(a), high16 = trunc-bf16(b).
__device__ __forceinline__ unsigned packbf(unsigned a, unsigned b) {
    return __builtin_amdgcn_perm(b, a, 0x07060302u);
}

// Exact 3-way truncation split: x == hi + mid + lo bit-exactly in fp32.
struct Split3 { unsigned h, m, l; };
__device__ __forceinline__ Split3 split3(float x) {
    unsigned xu = __float_as_uint(x);
    float xh = __uint_as_float(xu & 0xFFFF0000u);
    float r  = x - xh;                        // exact
    unsigned ru = __float_as_uint(r);
    float xm = __uint_as_float(ru & 0xFFFF0000u);
    float r2 = r - xm;                        // exact, fits bf16
    return { xu, ru, __float_as_uint(r2) };
}

// 2-way split: hi + residual (packbf of r truncates -> the mid limb).
struct Split2 { unsigned h, r; };
__device__ __forceinline__ Split2 split2(float x) {
    unsigned xu = __float_as_uint(x);
    float xh = __uint_as_float(xu & 0xFFFF0000u);
    float rr = x - xh;                        // exact residual
    return { xu, __float_as_uint(rr) };
}

// Wave-specialized (R13 structure). R14: tput loop unroll 2 -> 1 — the
// unroll doubled live front-end state in the TPUT branch and was the real
// source of the persistent ~48 MB scratch spill (march-side fixes in
// R12/R13 didn't move it). Per-eval issue (~570 cyc) > dependent chain
// (~360 cyc), so unroll-1 tput is already issue-bound; 3-wave TLP packs it.
// 128-thread blocks: wave0 = march (serial), wave1 = tput (65 indep evals).
// MFMA layouts (R6-verified): A[row=lane&15][k=quad*8+j],
// B[k=quad*8+j][col=lane&15], C/D col=lane&15 row=quad*4+reg.
// L1 hidden assignment H(t,q,r)=32*(t>>1)+8q+4*(t&1)+r -> in-lane C1->B2.
// Precision: march L2 = 3 products (m,h)(h,m)(h,h); tput L2 = 2 products.
__global__ __launch_bounds__(128, 3) void sdf_u1_k(
    const float* __restrict__ rays,
    const float* __restrict__ W0,  const float* __restrict__ b0,
    const float* __restrict__ W1,  const float* __restrict__ b1,
    const float* __restrict__ W2,  const float* __restrict__ b2,
    const float* __restrict__ Wr0, const float* __restrict__ br0,
    const float* __restrict__ Wr1, const float* __restrict__ br1,
    float* __restrict__ out)
{
    __shared__ uint4v a2mLds[8 * 64];         // 8 KB: 8 frags x 64 lanes

    const int lane = threadIdx.x & 63;
    const int kind = threadIdx.x >> 6;        // 0 = march, 1 = tput
    const int quad = lane >> 4;
    const int m    = lane & 15;
    const int rayBase = blockIdx.x * 16;

    // ---- per-lane ray (ray = rayBase + m, replicated over quads) ----
    const float* rp = rays + (rayBase + m) * 6;
    const float ox = rp[0], oy = rp[1], oz = rp[2];
    const float dx = rp[3], dy = rp[4], dz = rp[5];

    // ---- A1: exact W0^T/b0 limbs, uniform per-quad K-slots (R9-verified) ----
    short8 A1[4];
    {
        const float* wbase = (quad == 0) ? W0 : (quad == 1) ? (W0 + 64)
                           : (quad == 2) ? (W0 + 128) : b0;
        #pragma unroll
        for (int t = 0; t < 4; ++t) {
            int j = 32 * (t >> 1) + 8 * (m >> 2) + 4 * (t & 1) + (m & 3);
            Split3 s = split3(wbase[j]);
            unsigned hh = packbf(s.h, s.h);
            unsigned hm = packbf(s.h, s.m);
            unsigned ml = packbf(s.m, s.l);
            unsigned l0 = packbf(s.l, 0u);
            bool is3 = (quad == 3);
            A1[t] = mk_frag(is3 ? hm : hh, is3 ? l0 : hm, is3 ? 0u : ml, 0u);
        }
    }

    // ---- A2h: W1^T hi limb (both branches use it; 32 frag-regs) ----
    short8 A2h[2][4];
    #pragma unroll
    for (int h = 0; h < 2; ++h)
        #pragma unroll
        for (int t = 0; t < 4; ++t) {
            unsigned ph[4];
            #pragma unroll
            for (int jp = 0; jp < 4; ++jp) {
                int k0 = 32 * h + quad * 8 + 2 * jp;
                int j2 = 16 * t + m;
                ph[jp] = packbf(__float_as_uint(W1[k0 * 64 + j2]),
                                __float_as_uint(W1[(k0 + 1) * 64 + j2]));
            }
            A2h[h][t] = mk_frag(ph[0], ph[1], ph[2], ph[3]);
        }

    // ---- b1 (C2 init) and W2 (L3), per-lane rows j2 = 16t+4q+r ----
    float4v b1v[4], w2v[4];
    #pragma unroll
    for (int t = 0; t < 4; ++t) {
        int base = 16 * t + 4 * quad;
        b1v[t] = (float4v){b1[base], b1[base + 1], b1[base + 2], b1[base + 3]};
        w2v[t] = (float4v){W2[base], W2[base + 1], W2[base + 2], W2[base + 3]};
    }
    const float b2s = b2[0];
    const float4v z4 = {0.f, 0.f, 0.f, 0.f};

    // ---- branchless exact B1 build (R9/R10-verified) ----
    auto buildB1 = [&](float px, float py, float pz) -> short8 {
        float c = (quad == 0) ? px : (quad == 1) ? py : pz;
        Split3 s = split3(c);
        unsigned d0 = packbf(s.h, s.m);
        unsigned d1 = packbf(s.l, s.h);
        unsigned d2 = packbf(s.m, s.h);
        if (quad == 3) { d0 = 0x3F803F80u; d1 = 0x00003F80u; d2 = 0u; }
        return mk_frag(d0, d1, d2, 0u);
    };

    // ---- shared front-end: pos -> exact L1 -> relu -> split2 pack ----
    auto front = [&](float px, float py, float pz, short8* BH, short8* BM) {
        short8 B1 = buildB1(px, py, pz);
        float4v C1[4];
        #pragma unroll
        for (int t = 0; t < 4; ++t)
            C1[t] = __builtin_amdgcn_mfma_f32_16x16x32_bf16(A1[t], B1, z4, 0, 0, 0);
        unsigned PH[4][2], PM[4][2];
        #pragma unroll
        for (int t = 0; t < 4; ++t) {
            float v0 = fmaxf(C1[t][0], 0.f), v1 = fmaxf(C1[t][1], 0.f);
            float v2 = fmaxf(C1[t][2], 0.f), v3 = fmaxf(C1[t][3], 0.f);
            unsigned u0 = __float_as_uint(v0), u1 = __float_as_uint(v1);
            unsigned u2 = __float_as_uint(v2), u3 = __float_as_uint(v3);
            PH[t][0] = packbf(u0, u1); PH[t][1] = packbf(u2, u3);
            float r0 = v0 - __uint_as_float(u0 & 0xFFFF0000u);
            float r1 = v1 - __uint_as_float(u1 & 0xFFFF0000u);
            float r2 = v2 - __uint_as_float(u2 & 0xFFFF0000u);
            float r3 = v3 - __uint_as_float(u3 & 0xFFFF0000u);
            PM[t][0] = packbf(__float_as_uint(r0), __float_as_uint(r1));
            PM[t][1] = packbf(__float_as_uint(r2), __float_as_uint(r3));
        }
        #pragma unroll
        for (int h = 0; h < 2; ++h) {
            BH[h] = mk_frag(PH[2 * h][0], PH[2 * h][1],
                            PH[2 * h + 1][0], PH[2 * h + 1][1]);
            BM[h] = mk_frag(PM[2 * h][0], PM[2 * h][1],
                            PM[2 * h + 1][0], PM[2 * h + 1][1]);
        }
    };

    // ---- L3: in-lane relu*W2, 2 cross-quad shuffles -> d at every lane ----
    auto l3 = [&](const float4v* C2) -> float {
        float q0 = 0.f, q1 = 0.f, q2 = 0.f, q3 = 0.f;
        #pragma unroll
        for (int t = 0; t < 4; ++t) {
            q0 = fmaf(fmaxf(C2[t][0], 0.f), w2v[t][0], q0);
            q1 = fmaf(fmaxf(C2[t][1], 0.f), w2v[t][1], q1);
            q2 = fmaf(fmaxf(C2[t][2], 0.f), w2v[t][2], q2);
            q3 = fmaf(fmaxf(C2[t][3], 0.f), w2v[t][3], q3);
        }
        float part = (q0 + q1) + (q2 + q3);
        part += __shfl_xor(part, 16, 64);
        part += __shfl_xor(part, 32, 64);
        return b2s + part;
    };

    if (kind == 0) {
        // =================== MARCH wave: 64 sequential evals ===============
        // Build A2m (W1 mid limb) and park it in LDS (write once).
        #pragma unroll
        for (int h = 0; h < 2; ++h)
            #pragma unroll
            for (int t = 0; t < 4; ++t) {
                unsigned pm[4];
                #pragma unroll
                for (int jp = 0; jp < 4; ++jp) {
                    int k0 = 32 * h + quad * 8 + 2 * jp;
                    int j2 = 16 * t + m;
                    Split2 a = split2(W1[k0 * 64 + j2]);
                    Split2 b = split2(W1[(k0 + 1) * 64 + j2]);
                    pm[jp] = packbf(a.r, b.r);   // trunc(residual) == mid limb
                }
                a2mLds[(h * 4 + t) * 64 + lane] = (uint4v){pm[0], pm[1], pm[2], pm[3]};
            }

        bool  hit = false;
        float cd  = 0.f;
        #pragma unroll 1
        for (int it = 0; it < MARCH_ITERS; ++it) {
            if (__all(hit)) break;
            short8 BH[2], BM[2];
            front(fmaf(dx, cd, ox), fmaf(dy, cd, oy), fmaf(dz, cd, oz), BH, BM);
            // L2: 3 products, small first: (m,h)(h,m)(h,h); 24 MFMAs.
            float4v C2[4];
            #pragma unroll
            for (int t = 0; t < 4; ++t) C2[t] = b1v[t];
            #pragma unroll
            for (int h = 0; h < 2; ++h)
                #pragma unroll
                for (int t = 0; t < 4; ++t) {
                    short8 a2m = __builtin_bit_cast(short8,
                                     a2mLds[(h * 4 + t) * 64 + lane]);
                    C2[t] = __builtin_amdgcn_mfma_f32_16x16x32_bf16(
                        a2m, BH[h], C2[t], 0, 0, 0);
                }
            #pragma unroll
            for (int h = 0; h < 2; ++h)
                #pragma unroll
                for (int t = 0; t < 4; ++t)
                    C2[t] = __builtin_amdgcn_mfma_f32_16x16x32_bf16(
                        A2h[h][t], BM[h], C2[t], 0, 0, 0);
            #pragma unroll
            for (int h = 0; h < 2; ++h)
                #pragma unroll
                for (int t = 0; t < 4; ++t)
                    C2[t] = __builtin_amdgcn_mfma_f32_16x16x32_bf16(
                        A2h[h][t], BH[h], C2[t], 0, 0, 0);
            float dm = l3(C2);
            bool c = (dm < EPS_) && (cd >= 0.f) && (cd <= 1.f);
            hit = hit || c;
            if (!hit) cd += dm;
        }

        // ---- reflection net: quad q handles hidden j in [16q, 16q+16) ----
        const float px = fmaf(dx, cd, ox), py = fmaf(dy, cd, oy), pz = fmaf(dz, cd, oz);
        float r0 = 0.f, r1 = 0.f, r2 = 0.f;
        #pragma unroll 4
        for (int jj = 0; jj < 16; ++jj) {
            int j = quad * 16 + jj;
            float a = fmaf(px, Wr0[j],
                      fmaf(py, Wr0[64 + j],
                      fmaf(pz, Wr0[128 + j],
                      fmaf(dx, Wr0[192 + j],
                      fmaf(dy, Wr0[256 + j],
                      fmaf(dz, Wr0[320 + j], br0[j]))))));
            a = fmaxf(a, 0.f);
            r0 = fmaf(a, Wr1[j * 3 + 0], r0);
            r1 = fmaf(a, Wr1[j * 3 + 1], r1);
            r2 = fmaf(a, Wr1[j * 3 + 2], r2);
        }
        r0 += __shfl_xor(r0, 16, 64); r0 += __shfl_xor(r0, 32, 64);
        r1 += __shfl_xor(r1, 16, 64); r1 += __shfl_xor(r1, 32, 64);
        r2 += __shfl_xor(r2, 16, 64); r2 += __shfl_xor(r2, 32, 64);
        r0 = 1.f / (1.f + expf(-(r0 + br1[0])));
        r1 = 1.f / (1.f + expf(-(r1 + br1[1])));
        r2 = 1.f / (1.f + expf(-(r2 + br1[2])));
        if (!hit) { r0 = 0.f; r1 = 0.f; r2 = 0.f; }
        if (lane < 16) {
            float* op = out + (rayBase + lane) * 4;
            op[0] = r0; op[1] = r1; op[2] = r2;
        }
    } else {
        // =================== TPUT wave: 65 independent evals ===============
        // i=0 at origin (== reference curr_min0), then t = STEP*i.
        // unroll 1: per-eval issue (~570 cyc) > chain (~360 cyc) -> already
        // issue-bound; TLP (3 waves/SIMD) packs the pipes. No extra live state.
        float cm = 3.4e38f;
        #pragma unroll 1
        for (int i = 0; i <= 64; ++i) {
            float ti = STEP_ * (float)i;
            short8 BH[2], BM[2];
            front(fmaf(dx, ti, ox), fmaf(dy, ti, oy), fmaf(dz, ti, oz), BH, BM);
            // L2: 2 products (h,m)(h,h); 16 MFMAs
            float4v C2[4];
            #pragma unroll
            for (int t = 0; t < 4; ++t) C2[t] = b1v[t];
            #pragma unroll
            for (int h = 0; h < 2; ++h)
                #pragma unroll
                for (int t = 0; t < 4; ++t)
                    C2[t] = __builtin_amdgcn_mfma_f32_16x16x32_bf16(
                        A2h[h][t], BM[h], C2[t], 0, 0, 0);
            #pragma unroll
            for (int h = 0; h < 2; ++h)
                #pragma unroll
                for (int t = 0; t < 4; ++t)
                    C2[t] = __builtin_amdgcn_mfma_f32_16x16x32_bf16(
                        A2h[h][t], BH[h], C2[t], 0, 0, 0);
            float dt = l3(C2);
            cm = fminf(cm, dt);
        }
        if (lane < 16)
            out[(rayBase + lane) * 4 + 3] = cm;
    }
}

extern "C" void kernel_launch(void* const* d_in, const int* in_sizes, int n_in,
                              void* d_out, int out_size, void* d_ws, size_t ws_size,
                              hipStream_t stream) {
    const float* rays = (const float*)d_in[0];
    const float* W0   = (const float*)d_in[1];
    const float* b0   = (const float*)d_in[2];
    const float* W1   = (const float*)d_in[3];
    const float* b1   = (const float*)d_in[4];
    const float* W2   = (const float*)d_in[5];
    const float* b2   = (const float*)d_in[6];
    const float* Wr0  = (const float*)d_in[7];
    const float* br0  = (const float*)d_in[8];
    const float* Wr1  = (const float*)d_in[9];
    const float* br1  = (const float*)d_in[10];
    float* out = (float*)d_out;

    // 2048 blocks x 128 threads: wave0 = march, wave1 = tput per 16 rays.
    // 4096 waves; 3 waves/SIMD; tput loop unroll-1 (spill fix).
    hipLaunchKernelGGL(sdf_u1_k, dim3(NRAYS / 16), dim3(128), 0, stream,
                       rays, W0, b0, W1, b1, W2, b2, Wr0, br0, Wr1, br1, out);
}

// Round 15
// 179.152 us; speedup vs baseline: 1.0606x; 1.0392x over previous
//
#include <hip/hip_runtime.h>
#include <math.h>

// Problem constants
#define NRAYS        32768
#define MARCH_ITERS  64
#define EPS_         1e-4f
#define STEP_        ((1.0f + 1.0f/64.0f) / 64.0f)   // exact in fp32

typedef __attribute__((ext_vector_type(8)))  short    short8;   // 8 bf16
typedef __attribute__((ext_vector_type(4)))  float    float4v;  // C/D frag
typedef __attribute__((ext_vector_type(4)))  unsigned uint4v;

__device__ __forceinline__ short8 mk_frag(unsigned p0, unsigned p1,
                                          unsigned p2, unsigned p3) {
    uint4v v = {p0, p1, p2, p3};
    return __builtin_bit_cast(short8, v);
}

// One v_perm_b32: low16 = trunc-bf16(a), high16 = trunc-bf16(b).
__device__ __forceinline__ unsigned packbf(unsigned a, unsigned b) {
    return __builtin_amdgcn_perm(b, a, 0x07060302u);
}

// Exact 3-way truncation split: x == hi + mid + lo bit-exactly in fp32.
struct Split3 { unsigned h, m, l; };
__device__ __forceinline__ Split3 split3(float x) {
    unsigned xu = __float_as_uint(x);
    float xh = __uint_as_float(xu & 0xFFFF0000u);
    float r  = x - xh;                        // exact
    unsigned ru = __float_as_uint(r);
    float xm = __uint_as_float(ru & 0xFFFF0000u);
    float r2 = r - xm;                        // exact, fits bf16
    return { xu, ru, __float_as_uint(r2) };
}

// 2-way split: hi + residual (packbf of r truncates -> the mid limb).
struct Split2 { unsigned h, r; };
__device__ __forceinline__ Split2 split2(float x) {
    unsigned xu = __float_as_uint(x);
    float xh = __uint_as_float(xu & 0xFFFF0000u);
    float rr = x - xh;                        // exact residual
    return { xu, __float_as_uint(rr) };
}

// Wave-specialized (R14 structure). R15: A2h (W1 hi-limb frags) parked in
// LDS alongside A2m — A2h is wave-invariant per block, so ONE copy serves
// both waves (march reads a2m+a2h, tput reads a2h). Freeing those 32
// loop-carried regs lets us drop to __launch_bounds__(128,4): 4 waves/SIMD
// resident to cover the march chain's latency (R14 stall fraction ~33%).
// 128-thread blocks: wave0 = march (serial), wave1 = tput (65 indep evals).
// MFMA layouts (R6-verified): A[row=lane&15][k=quad*8+j],
// B[k=quad*8+j][col=lane&15], C/D col=lane&15 row=quad*4+reg.
// L1 hidden assignment H(t,q,r)=32*(t>>1)+8q+4*(t&1)+r -> in-lane C1->B2.
// Precision: march L2 = 3 products (m,h)(h,m)(h,h); tput L2 = 2 products.
__global__ __launch_bounds__(128, 4) void sdf_w4_k(
    const float* __restrict__ rays,
    const float* __restrict__ W0,  const float* __restrict__ b0,
    const float* __restrict__ W1,  const float* __restrict__ b1,
    const float* __restrict__ W2,  const float* __restrict__ b2,
    const float* __restrict__ Wr0, const float* __restrict__ br0,
    const float* __restrict__ Wr1, const float* __restrict__ br1,
    float* __restrict__ out)
{
    __shared__ uint4v a2mLds[8 * 64];         // 8 KB: W1 mid-limb frags
    __shared__ uint4v a2hLds[8 * 64];         // 8 KB: W1 hi-limb frags

    const int lane = threadIdx.x & 63;
    const int kind = threadIdx.x >> 6;        // 0 = march, 1 = tput
    const int quad = lane >> 4;
    const int m    = lane & 15;
    const int rayBase = blockIdx.x * 16;

    // ---- per-lane ray (ray = rayBase + m, replicated over quads) ----
    const float* rp = rays + (rayBase + m) * 6;
    const float ox = rp[0], oy = rp[1], oz = rp[2];
    const float dx = rp[3], dy = rp[4], dz = rp[5];

    // ---- A1: exact W0^T/b0 limbs, uniform per-quad K-slots (R9-verified) ----
    short8 A1[4];
    {
        const float* wbase = (quad == 0) ? W0 : (quad == 1) ? (W0 + 64)
                           : (quad == 2) ? (W0 + 128) : b0;
        #pragma unroll
        for (int t = 0; t < 4; ++t) {
            int j = 32 * (t >> 1) + 8 * (m >> 2) + 4 * (t & 1) + (m & 3);
            Split3 s = split3(wbase[j]);
            unsigned hh = packbf(s.h, s.h);
            unsigned hm = packbf(s.h, s.m);
            unsigned ml = packbf(s.m, s.l);
            unsigned l0 = packbf(s.l, 0u);
            bool is3 = (quad == 3);
            A1[t] = mk_frag(is3 ? hm : hh, is3 ? l0 : hm, is3 ? 0u : ml, 0u);
        }
    }

    // ---- cooperative W1 limb staging: wave0 -> a2m, wave1 -> a2h ----
    if (kind == 0) {
        #pragma unroll
        for (int h = 0; h < 2; ++h)
            #pragma unroll
            for (int t = 0; t < 4; ++t) {
                unsigned pm[4];
                #pragma unroll
                for (int jp = 0; jp < 4; ++jp) {
                    int k0 = 32 * h + quad * 8 + 2 * jp;
                    int j2 = 16 * t + m;
                    Split2 a = split2(W1[k0 * 64 + j2]);
                    Split2 b = split2(W1[(k0 + 1) * 64 + j2]);
                    pm[jp] = packbf(a.r, b.r);   // trunc(residual) == mid limb
                }
                a2mLds[(h * 4 + t) * 64 + lane] = (uint4v){pm[0], pm[1], pm[2], pm[3]};
            }
    } else {
        #pragma unroll
        for (int h = 0; h < 2; ++h)
            #pragma unroll
            for (int t = 0; t < 4; ++t) {
                unsigned ph[4];
                #pragma unroll
                for (int jp = 0; jp < 4; ++jp) {
                    int k0 = 32 * h + quad * 8 + 2 * jp;
                    int j2 = 16 * t + m;
                    ph[jp] = packbf(__float_as_uint(W1[k0 * 64 + j2]),
                                    __float_as_uint(W1[(k0 + 1) * 64 + j2]));
                }
                a2hLds[(h * 4 + t) * 64 + lane] = (uint4v){ph[0], ph[1], ph[2], ph[3]};
            }
    }
    __syncthreads();                           // one-time; loops are sync-free

    // ---- b1 (C2 init) and W2 (L3), per-lane rows j2 = 16t+4q+r ----
    float4v b1v[4], w2v[4];
    #pragma unroll
    for (int t = 0; t < 4; ++t) {
        int base = 16 * t + 4 * quad;
        b1v[t] = (float4v){b1[base], b1[base + 1], b1[base + 2], b1[base + 3]};
        w2v[t] = (float4v){W2[base], W2[base + 1], W2[base + 2], W2[base + 3]};
    }
    const float b2s = b2[0];
    const float4v z4 = {0.f, 0.f, 0.f, 0.f};

    // ---- branchless exact B1 build (R9/R10-verified) ----
    auto buildB1 = [&](float px, float py, float pz) -> short8 {
        float c = (quad == 0) ? px : (quad == 1) ? py : pz;
        Split3 s = split3(c);
        unsigned d0 = packbf(s.h, s.m);
        unsigned d1 = packbf(s.l, s.h);
        unsigned d2 = packbf(s.m, s.h);
        if (quad == 3) { d0 = 0x3F803F80u; d1 = 0x00003F80u; d2 = 0u; }
        return mk_frag(d0, d1, d2, 0u);
    };

    // ---- shared front-end: pos -> exact L1 -> relu -> split2 pack ----
    auto front = [&](float px, float py, float pz, short8* BH, short8* BM) {
        short8 B1 = buildB1(px, py, pz);
        float4v C1[4];
        #pragma unroll
        for (int t = 0; t < 4; ++t)
            C1[t] = __builtin_amdgcn_mfma_f32_16x16x32_bf16(A1[t], B1, z4, 0, 0, 0);
        unsigned PH[4][2], PM[4][2];
        #pragma unroll
        for (int t = 0; t < 4; ++t) {
            float v0 = fmaxf(C1[t][0], 0.f), v1 = fmaxf(C1[t][1], 0.f);
            float v2 = fmaxf(C1[t][2], 0.f), v3 = fmaxf(C1[t][3], 0.f);
            unsigned u0 = __float_as_uint(v0), u1 = __float_as_uint(v1);
            unsigned u2 = __float_as_uint(v2), u3 = __float_as_uint(v3);
            PH[t][0] = packbf(u0, u1); PH[t][1] = packbf(u2, u3);
            float r0 = v0 - __uint_as_float(u0 & 0xFFFF0000u);
            float r1 = v1 - __uint_as_float(u1 & 0xFFFF0000u);
            float r2 = v2 - __uint_as_float(u2 & 0xFFFF0000u);
            float r3 = v3 - __uint_as_float(u3 & 0xFFFF0000u);
            PM[t][0] = packbf(__float_as_uint(r0), __float_as_uint(r1));
            PM[t][1] = packbf(__float_as_uint(r2), __float_as_uint(r3));
        }
        #pragma unroll
        for (int h = 0; h < 2; ++h) {
            BH[h] = mk_frag(PH[2 * h][0], PH[2 * h][1],
                            PH[2 * h + 1][0], PH[2 * h + 1][1]);
            BM[h] = mk_frag(PM[2 * h][0], PM[2 * h][1],
                            PM[2 * h + 1][0], PM[2 * h + 1][1]);
        }
    };

    // ---- L3: in-lane relu*W2, 2 cross-quad shuffles -> d at every lane ----
    auto l3 = [&](const float4v* C2) -> float {
        float q0 = 0.f, q1 = 0.f, q2 = 0.f, q3 = 0.f;
        #pragma unroll
        for (int t = 0; t < 4; ++t) {
            q0 = fmaf(fmaxf(C2[t][0], 0.f), w2v[t][0], q0);
            q1 = fmaf(fmaxf(C2[t][1], 0.f), w2v[t][1], q1);
            q2 = fmaf(fmaxf(C2[t][2], 0.f), w2v[t][2], q2);
            q3 = fmaf(fmaxf(C2[t][3], 0.f), w2v[t][3], q3);
        }
        float part = (q0 + q1) + (q2 + q3);
        part += __shfl_xor(part, 16, 64);
        part += __shfl_xor(part, 32, 64);
        return b2s + part;
    };

    auto ldsFrag = [&](const uint4v* base, int h, int t) -> short8 {
        return __builtin_bit_cast(short8, base[(h * 4 + t) * 64 + lane]);
    };

    if (kind == 0) {
        // =================== MARCH wave: 64 sequential evals ===============
        bool  hit = false;
        float cd  = 0.f;
        #pragma unroll 1
        for (int it = 0; it < MARCH_ITERS; ++it) {
            if (__all(hit)) break;
            short8 BH[2], BM[2];
            front(fmaf(dx, cd, ox), fmaf(dy, cd, oy), fmaf(dz, cd, oz), BH, BM);
            // L2: 3 products, small first: (m,h)(h,m)(h,h); 24 MFMAs.
            // Both W1 limbs stream from LDS (per-iter transients).
            float4v C2[4];
            #pragma unroll
            for (int t = 0; t < 4; ++t) C2[t] = b1v[t];
            #pragma unroll
            for (int h = 0; h < 2; ++h)
                #pragma unroll
                for (int t = 0; t < 4; ++t)
                    C2[t] = __builtin_amdgcn_mfma_f32_16x16x32_bf16(
                        ldsFrag(a2mLds, h, t), BH[h], C2[t], 0, 0, 0);
            #pragma unroll
            for (int h = 0; h < 2; ++h)
                #pragma unroll
                for (int t = 0; t < 4; ++t)
                    C2[t] = __builtin_amdgcn_mfma_f32_16x16x32_bf16(
                        ldsFrag(a2hLds, h, t), BM[h], C2[t], 0, 0, 0);
            #pragma unroll
            for (int h = 0; h < 2; ++h)
                #pragma unroll
                for (int t = 0; t < 4; ++t)
                    C2[t] = __builtin_amdgcn_mfma_f32_16x16x32_bf16(
                        ldsFrag(a2hLds, h, t), BH[h], C2[t], 0, 0, 0);
            float dm = l3(C2);
            bool c = (dm < EPS_) && (cd >= 0.f) && (cd <= 1.f);
            hit = hit || c;
            if (!hit) cd += dm;
        }

        // ---- reflection net: quad q handles hidden j in [16q, 16q+16) ----
        const float px = fmaf(dx, cd, ox), py = fmaf(dy, cd, oy), pz = fmaf(dz, cd, oz);
        float r0 = 0.f, r1 = 0.f, r2 = 0.f;
        #pragma unroll 4
        for (int jj = 0; jj < 16; ++jj) {
            int j = quad * 16 + jj;
            float a = fmaf(px, Wr0[j],
                      fmaf(py, Wr0[64 + j],
                      fmaf(pz, Wr0[128 + j],
                      fmaf(dx, Wr0[192 + j],
                      fmaf(dy, Wr0[256 + j],
                      fmaf(dz, Wr0[320 + j], br0[j]))))));
            a = fmaxf(a, 0.f);
            r0 = fmaf(a, Wr1[j * 3 + 0], r0);
            r1 = fmaf(a, Wr1[j * 3 + 1], r1);
            r2 = fmaf(a, Wr1[j * 3 + 2], r2);
        }
        r0 += __shfl_xor(r0, 16, 64); r0 += __shfl_xor(r0, 32, 64);
        r1 += __shfl_xor(r1, 16, 64); r1 += __shfl_xor(r1, 32, 64);
        r2 += __shfl_xor(r2, 16, 64); r2 += __shfl_xor(r2, 32, 64);
        r0 = 1.f / (1.f + expf(-(r0 + br1[0])));
        r1 = 1.f / (1.f + expf(-(r1 + br1[1])));
        r2 = 1.f / (1.f + expf(-(r2 + br1[2])));
        if (!hit) { r0 = 0.f; r1 = 0.f; r2 = 0.f; }
        if (lane < 16) {
            float* op = out + (rayBase + lane) * 4;
            op[0] = r0; op[1] = r1; op[2] = r2;
        }
    } else {
        // =================== TPUT wave: 65 independent evals ===============
        // i=0 at origin (== reference curr_min0), then t = STEP*i. unroll-1.
        float cm = 3.4e38f;
        #pragma unroll 1
        for (int i = 0; i <= 64; ++i) {
            float ti = STEP_ * (float)i;
            short8 BH[2], BM[2];
            front(fmaf(dx, ti, ox), fmaf(dy, ti, oy), fmaf(dz, ti, oz), BH, BM);
            // L2: 2 products (h,m)(h,h); 16 MFMAs; A2h streams from LDS.
            float4v C2[4];
            #pragma unroll
            for (int t = 0; t < 4; ++t) C2[t] = b1v[t];
            #pragma unroll
            for (int h = 0; h < 2; ++h)
                #pragma unroll
                for (int t = 0; t < 4; ++t)
                    C2[t] = __builtin_amdgcn_mfma_f32_16x16x32_bf16(
                        ldsFrag(a2hLds, h, t), BM[h], C2[t], 0, 0, 0);
            #pragma unroll
            for (int h = 0; h < 2; ++h)
                #pragma unroll
                for (int t = 0; t < 4; ++t)
                    C2[t] = __builtin_amdgcn_mfma_f32_16x16x32_bf16(
                        ldsFrag(a2hLds, h, t), BH[h], C2[t], 0, 0, 0);
            float dt = l3(C2);
            cm = fminf(cm, dt);
        }
        if (lane < 16)
            out[(rayBase + lane) * 4 + 3] = cm;
    }
}

extern "C" void kernel_launch(void* const* d_in, const int* in_sizes, int n_in,
                              void* d_out, int out_size, void* d_ws, size_t ws_size,
                              hipStream_t stream) {
    const float* rays = (const float*)d_in[0];
    const float* W0   = (const float*)d_in[1];
    const float* b0   = (const float*)d_in[2];
    const float* W1   = (const float*)d_in[3];
    const float* b1   = (const float*)d_in[4];
    const float* W2   = (const float*)d_in[5];
    const float* b2   = (const float*)d_in[6];
    const float* Wr0  = (const float*)d_in[7];
    const float* br0  = (const float*)d_in[8];
    const float* Wr1  = (const float*)d_in[9];
    const float* br1  = (const float*)d_in[10];
    float* out = (float*)d_out;

    // 2048 blocks x 128 threads: wave0 = march, wave1 = tput per 16 rays.
    // W1 limbs in LDS (16 KB/block, one copy per block serves both waves);
    // __launch_bounds__(128,4) -> 4 waves/SIMD to cover march latency.
    hipLaunchKernelGGL(sdf_w4_k, dim3(NRAYS / 16), dim3(128), 0, stream,
                       rays, W0, b0, W1, b1, W2, b2, Wr0, br0, Wr1, br1, out);
}